// Round 1
// baseline (486.695 us; speedup 1.0000x reference)
//
#include <hip/hip_runtime.h>

// Problem constants (fixed by setup_inputs): N=262144, D=32, Q=4, K=256
#define DIMS 32
#define NQ   4
#define KC   256
#define BETA 0.25f

__launch_bounds__(256)
__global__ void rvq_kernel(const float* __restrict__ x,
                           const float* __restrict__ cb,      // [NQ, KC, DIMS]
                           float* __restrict__ out_xq,        // [N, DIMS]
                           float* __restrict__ out_loss,      // [1] (pre-zeroed)
                           float* __restrict__ out_idx,       // [N, NQ] as float
                           int N)
{
    // ---- per-block: codebook norms into LDS (uniform data, 4 KB) ----
    __shared__ float s_norms[NQ * KC];
    for (int i = threadIdx.x; i < NQ * KC; i += 256) {
        const float* c = cb + (size_t)i * DIMS;
        float s0 = 0.f, s1 = 0.f, s2 = 0.f, s3 = 0.f;
        #pragma unroll
        for (int d = 0; d < DIMS; d += 4) {
            float4 t = *(const float4*)(c + d);
            s0 = fmaf(t.x, t.x, s0);
            s1 = fmaf(t.y, t.y, s1);
            s2 = fmaf(t.z, t.z, s2);
            s3 = fmaf(t.w, t.w, s3);
        }
        s_norms[i] = (s0 + s1) + (s2 + s3);
    }
    __syncthreads();

    const int n = blockIdx.x * 256 + threadIdx.x;

    // ---- load residual (= x) into registers ----
    float r[DIMS];
    {
        const float4* xv = (const float4*)(x + (size_t)n * DIMS);
        #pragma unroll
        for (int i = 0; i < DIMS / 4; ++i) {
            float4 t = xv[i];
            r[4*i+0] = t.x; r[4*i+1] = t.y; r[4*i+2] = t.z; r[4*i+3] = t.w;
        }
    }
    float xq[DIMS];
    #pragma unroll
    for (int d = 0; d < DIMS; ++d) xq[d] = 0.f;

    float lossAcc = 0.f;
    int   idxs[NQ];

    #pragma unroll
    for (int q = 0; q < NQ; ++q) {
        const float* cbq = cb + (size_t)q * KC * DIMS;   // wave-uniform pointer

        // ||r||^2 (needed only for the loss)
        float rn0 = 0.f, rn1 = 0.f, rn2 = 0.f, rn3 = 0.f;
        #pragma unroll
        for (int d = 0; d < DIMS; d += 4) {
            rn0 = fmaf(r[d+0], r[d+0], rn0);
            rn1 = fmaf(r[d+1], r[d+1], rn1);
            rn2 = fmaf(r[d+2], r[d+2], rn2);
            rn3 = fmaf(r[d+3], r[d+3], rn3);
        }
        const float rnorm = (rn0 + rn1) + (rn2 + rn3);

        float best = 3.402823466e38f;
        int   bi   = 0;

        // hot loop: codebook accesses are wave-uniform -> s_load + SGPR-operand FMAs
        #pragma unroll 2
        for (int k = 0; k < KC; ++k) {
            const float* ck = cbq + k * DIMS;
            float a0 = 0.f, a1 = 0.f, a2 = 0.f, a3 = 0.f;
            #pragma unroll
            for (int d = 0; d < DIMS; d += 4) {
                a0 = fmaf(r[d+0], ck[d+0], a0);
                a1 = fmaf(r[d+1], ck[d+1], a1);
                a2 = fmaf(r[d+2], ck[d+2], a2);
                a3 = fmaf(r[d+3], ck[d+3], a3);
            }
            const float dot   = (a0 + a1) + (a2 + a3);
            const float score = fmaf(-2.f, dot, s_norms[q * KC + k]);
            const bool  lt    = score < best;   // strict: first-occurrence tie-break
            best = lt ? score : best;
            bi   = lt ? k : bi;
        }

        idxs[q]  = bi;
        lossAcc += best + rnorm;   // == min squared distance

        // gather chosen code, update residual and x_q
        const float4* qv = (const float4*)(cbq + (size_t)bi * DIMS);
        #pragma unroll
        for (int i = 0; i < DIMS / 4; ++i) {
            float4 t = qv[i];
            r[4*i+0] -= t.x;  xq[4*i+0] += t.x;
            r[4*i+1] -= t.y;  xq[4*i+1] += t.y;
            r[4*i+2] -= t.z;  xq[4*i+2] += t.z;
            r[4*i+3] -= t.w;  xq[4*i+3] += t.w;
        }
    }

    // ---- store x_q ----
    {
        float4* ov = (float4*)(out_xq + (size_t)n * DIMS);
        #pragma unroll
        for (int i = 0; i < DIMS / 4; ++i)
            ov[i] = make_float4(xq[4*i+0], xq[4*i+1], xq[4*i+2], xq[4*i+3]);
    }

    // ---- store indices (base is only 4B-aligned: scalar stores) ----
    #pragma unroll
    for (int q = 0; q < NQ; ++q)
        out_idx[(size_t)n * NQ + q] = (float)idxs[q];

    // ---- loss reduction: wave -> block -> one atomicAdd ----
    float v = lossAcc;
    #pragma unroll
    for (int off = 32; off > 0; off >>= 1)
        v += __shfl_down(v, off, 64);

    __shared__ float s_ws[4];
    const int wid = threadIdx.x >> 6;
    if ((threadIdx.x & 63) == 0) s_ws[wid] = v;
    __syncthreads();
    if (threadIdx.x == 0) {
        const float blockSum = (s_ws[0] + s_ws[1]) + (s_ws[2] + s_ws[3]);
        const float scale = (1.0f + BETA) / ((float)NQ * (float)N * (float)DIMS);
        atomicAdd(out_loss, blockSum * scale);
    }
}

extern "C" void kernel_launch(void* const* d_in, const int* in_sizes, int n_in,
                              void* d_out, int out_size, void* d_ws, size_t ws_size,
                              hipStream_t stream) {
    const float* x  = (const float*)d_in[0];   // [N, 32]
    const float* cb = (const float*)d_in[1];   // [4, 256, 32]
    float* out = (float*)d_out;

    const int N = in_sizes[0] / DIMS;          // 262144
    float* out_xq   = out;
    float* out_loss = out + (size_t)N * DIMS;
    float* out_idx  = out + (size_t)N * DIMS + 1;

    // zero the loss accumulator slot (graph-capture legal)
    hipMemsetAsync(out_loss, 0, sizeof(float), stream);

    rvq_kernel<<<dim3(N / 256), dim3(256), 0, stream>>>(x, cb, out_xq, out_loss, out_idx, N);
}

// Round 2
// 384.862 us; speedup vs baseline: 1.2646x; 1.2646x over previous
//
#include <hip/hip_runtime.h>

// Problem constants (fixed by setup_inputs): N=262144, D=32, Q=4, K=256
#define DIMS 32
#define NQ   4
#define KC   256
#define BETA 0.25f

// 256 threads/block, M=2 points/thread -> 512 points/block, grid = 512.
// __launch_bounds__(256,4): cap VGPR at 128 so 4 blocks/CU *can* be resident.
__launch_bounds__(256, 4)
__global__ void rvq_kernel(const float* __restrict__ x,
                           const float* __restrict__ cb,      // [NQ, KC, DIMS]
                           float* __restrict__ out_xq,        // [N, DIMS]
                           float* __restrict__ out_loss,      // [1] (pre-zeroed)
                           float* __restrict__ out_idx)       // [N, NQ] as float
{
    __shared__ float4 s_cb[KC * DIMS / 4];   // 32 KB: one stage's codebook
    __shared__ float  s_norm[KC];            // 1 KB: code norms

    const int t  = threadIdx.x;
    const int n0 = blockIdx.x * 512 + t;
    const int n1 = n0 + 256;

    // ---- residuals for 2 points in registers (64 VGPRs) ----
    float r0[DIMS], r1[DIMS];
    {
        const float4* xv0 = (const float4*)(x + (size_t)n0 * DIMS);
        const float4* xv1 = (const float4*)(x + (size_t)n1 * DIMS);
        #pragma unroll
        for (int i = 0; i < 8; ++i) {
            float4 a = xv0[i], b = xv1[i];
            r0[4*i+0] = a.x; r0[4*i+1] = a.y; r0[4*i+2] = a.z; r0[4*i+3] = a.w;
            r1[4*i+0] = b.x; r1[4*i+1] = b.y; r1[4*i+2] = b.z; r1[4*i+3] = b.w;
        }
    }

    float lossAcc = 0.f;
    int idx0[NQ], idx1[NQ];

    for (int q = 0; q < NQ; ++q) {
        __syncthreads();   // previous stage's LDS reads complete before restage

        // ---- stage codebook q into LDS (coalesced float4) ----
        const float4* cb4 = (const float4*)(cb + (size_t)q * KC * DIMS);
        #pragma unroll
        for (int j = 0; j < 8; ++j)
            s_cb[j * 256 + t] = cb4[j * 256 + t];

        // ---- thread t computes norm of code t (global reads, L2-hot) ----
        {
            const float* c = cb + (size_t)q * KC * DIMS + (size_t)t * DIMS;
            float s0 = 0.f, s1 = 0.f, s2 = 0.f, s3 = 0.f;
            #pragma unroll
            for (int d = 0; d < DIMS; d += 4) {
                s0 = fmaf(c[d+0], c[d+0], s0);
                s1 = fmaf(c[d+1], c[d+1], s1);
                s2 = fmaf(c[d+2], c[d+2], s2);
                s3 = fmaf(c[d+3], c[d+3], s3);
            }
            s_norm[t] = (s0 + s1) + (s2 + s3);
        }
        __syncthreads();

        // ---- ||r||^2 per point (loss only) ----
        float rn0, rn1;
        {
            float u0=0.f,u1=0.f,u2=0.f,u3=0.f, v0=0.f,v1=0.f,v2=0.f,v3=0.f;
            #pragma unroll
            for (int d = 0; d < DIMS; d += 4) {
                u0 = fmaf(r0[d+0], r0[d+0], u0);
                u1 = fmaf(r0[d+1], r0[d+1], u1);
                u2 = fmaf(r0[d+2], r0[d+2], u2);
                u3 = fmaf(r0[d+3], r0[d+3], u3);
                v0 = fmaf(r1[d+0], r1[d+0], v0);
                v1 = fmaf(r1[d+1], r1[d+1], v1);
                v2 = fmaf(r1[d+2], r1[d+2], v2);
                v3 = fmaf(r1[d+3], r1[d+3], v3);
            }
            rn0 = (u0 + u1) + (u2 + u3);
            rn1 = (v0 + v1) + (v2 + v3);
        }

        // ---- hot loop: broadcast LDS reads, 2 dot products per row ----
        float best0 = 3.402823466e38f, best1 = 3.402823466e38f;
        int   bi0 = 0, bi1 = 0;

        #pragma unroll 2
        for (int k = 0; k < KC; ++k) {
            const float4* row = s_cb + k * 8;
            float a0=0.f,a1=0.f,a2=0.f,a3=0.f, b0=0.f,b1=0.f,b2=0.f,b3=0.f;
            #pragma unroll
            for (int j = 0; j < 8; ++j) {
                float4 c = row[j];
                a0 = fmaf(r0[4*j+0], c.x, a0);
                a1 = fmaf(r0[4*j+1], c.y, a1);
                a2 = fmaf(r0[4*j+2], c.z, a2);
                a3 = fmaf(r0[4*j+3], c.w, a3);
                b0 = fmaf(r1[4*j+0], c.x, b0);
                b1 = fmaf(r1[4*j+1], c.y, b1);
                b2 = fmaf(r1[4*j+2], c.z, b2);
                b3 = fmaf(r1[4*j+3], c.w, b3);
            }
            const float nrm = s_norm[k];
            const float sc0 = fmaf(-2.f, (a0 + a1) + (a2 + a3), nrm);
            const float sc1 = fmaf(-2.f, (b0 + b1) + (b2 + b3), nrm);
            const bool l0 = sc0 < best0;            // strict <: first-occurrence tie-break
            best0 = l0 ? sc0 : best0;  bi0 = l0 ? k : bi0;
            const bool l1 = sc1 < best1;
            best1 = l1 ? sc1 : best1;  bi1 = l1 ? k : bi1;
        }

        idx0[q] = bi0;  idx1[q] = bi1;
        lossAcc += (best0 + rn0) + (best1 + rn1);   // == sum of min squared dists

        // ---- gather chosen codes from global (L2/L3-hot), update residuals ----
        const float4* c0 = (const float4*)(cb + ((size_t)q * KC + bi0) * DIMS);
        const float4* c1 = (const float4*)(cb + ((size_t)q * KC + bi1) * DIMS);
        #pragma unroll
        for (int i = 0; i < 8; ++i) {
            float4 a = c0[i], b = c1[i];
            r0[4*i+0] -= a.x; r0[4*i+1] -= a.y; r0[4*i+2] -= a.z; r0[4*i+3] -= a.w;
            r1[4*i+0] -= b.x; r1[4*i+1] -= b.y; r1[4*i+2] -= b.z; r1[4*i+3] -= b.w;
        }
    }

    // ---- epilogue: x_q = x - r_final (reload x; it's L3-hot) ----
    {
        const float4* xv0 = (const float4*)(x + (size_t)n0 * DIMS);
        const float4* xv1 = (const float4*)(x + (size_t)n1 * DIMS);
        float4* ov0 = (float4*)(out_xq + (size_t)n0 * DIMS);
        float4* ov1 = (float4*)(out_xq + (size_t)n1 * DIMS);
        #pragma unroll
        for (int i = 0; i < 8; ++i) {
            float4 xa = xv0[i], xb = xv1[i];
            ov0[i] = make_float4(xa.x - r0[4*i+0], xa.y - r0[4*i+1],
                                 xa.z - r0[4*i+2], xa.w - r0[4*i+3]);
            ov1[i] = make_float4(xb.x - r1[4*i+0], xb.y - r1[4*i+1],
                                 xb.z - r1[4*i+2], xb.w - r1[4*i+3]);
        }
    }

    // ---- indices ----
    #pragma unroll
    for (int q = 0; q < NQ; ++q) {
        out_idx[(size_t)n0 * NQ + q] = (float)idx0[q];
        out_idx[(size_t)n1 * NQ + q] = (float)idx1[q];
    }

    // ---- loss: wave -> block -> one atomicAdd ----
    float v = lossAcc;
    #pragma unroll
    for (int off = 32; off > 0; off >>= 1)
        v += __shfl_down(v, off, 64);

    __shared__ float s_ws[4];
    const int wid = threadIdx.x >> 6;
    if ((threadIdx.x & 63) == 0) s_ws[wid] = v;
    __syncthreads();
    if (threadIdx.x == 0) {
        const float blockSum = (s_ws[0] + s_ws[1]) + (s_ws[2] + s_ws[3]);
        const float scale = (1.0f + BETA) / ((float)NQ * 262144.0f * (float)DIMS);
        atomicAdd(out_loss, blockSum * scale);
    }
}

extern "C" void kernel_launch(void* const* d_in, const int* in_sizes, int n_in,
                              void* d_out, int out_size, void* d_ws, size_t ws_size,
                              hipStream_t stream) {
    const float* x  = (const float*)d_in[0];   // [N, 32]
    const float* cb = (const float*)d_in[1];   // [4, 256, 32]
    float* out = (float*)d_out;

    const int N = in_sizes[0] / DIMS;          // 262144
    float* out_xq   = out;
    float* out_loss = out + (size_t)N * DIMS;
    float* out_idx  = out + (size_t)N * DIMS + 1;

    hipMemsetAsync(out_loss, 0, sizeof(float), stream);

    rvq_kernel<<<dim3(N / 512), dim3(256), 0, stream>>>(x, cb, out_xq, out_loss, out_idx);
}

// Round 3
// 351.988 us; speedup vs baseline: 1.3827x; 1.0934x over previous
//
#include <hip/hip_runtime.h>

// Problem constants (fixed by setup_inputs): N=262144, D=32, Q=4, K=256
#define DIMS 32
#define NQ   4
#define KC   256
#define BETA 0.25f

// Codebook rows are wave-uniform -> compiler keeps them in SGPRs (s_load_dwordx16).
// Explicit A/B double-buffer gives each scalar load a full scoring-iteration
// (~146 VALU cyc) of latency distance. FMAs are v_fmac(v_acc, s_row, v_resid):
// zero LDS / zero VMEM traffic in the hot loop.
#define LOAD_ROW(DST, KIDX)                                              \
    _Pragma("unroll")                                                    \
    for (int d = 0; d < DIMS; ++d) (DST)[d] = cbq[(KIDX) * DIMS + d];

#define SCORE_ROW(ROW, KIDX)                                             \
    {                                                                    \
        float a0=0.f,a1=0.f,a2=0.f,a3=0.f, b0=0.f,b1=0.f,b2=0.f,b3=0.f;  \
        _Pragma("unroll")                                                \
        for (int d = 0; d < DIMS; d += 4) {                              \
            a0 = fmaf(r0[d+0], (ROW)[d+0], a0);                          \
            a1 = fmaf(r0[d+1], (ROW)[d+1], a1);                          \
            a2 = fmaf(r0[d+2], (ROW)[d+2], a2);                          \
            a3 = fmaf(r0[d+3], (ROW)[d+3], a3);                          \
            b0 = fmaf(r1[d+0], (ROW)[d+0], b0);                          \
            b1 = fmaf(r1[d+1], (ROW)[d+1], b1);                          \
            b2 = fmaf(r1[d+2], (ROW)[d+2], b2);                          \
            b3 = fmaf(r1[d+3], (ROW)[d+3], b3);                          \
        }                                                                \
        const float nrm = s_norm[(KIDX)];                                \
        const float sc0 = fmaf(-2.f, (a0 + a1) + (a2 + a3), nrm);        \
        const float sc1 = fmaf(-2.f, (b0 + b1) + (b2 + b3), nrm);        \
        const bool l0 = sc0 < best0;  /* strict <: first-occurrence */   \
        best0 = l0 ? sc0 : best0;  bi0 = l0 ? (KIDX) : bi0;              \
        const bool l1 = sc1 < best1;                                     \
        best1 = l1 ? sc1 : best1;  bi1 = l1 ? (KIDX) : bi1;              \
    }

__launch_bounds__(256, 2)
__global__ void rvq_kernel(const float* __restrict__ x,
                           const float* __restrict__ cb,      // [NQ, KC, DIMS]
                           float* __restrict__ out_xq,        // [N, DIMS]
                           float* __restrict__ out_loss,      // [1] (pre-zeroed)
                           float* __restrict__ out_idx)       // [N, NQ] as float
{
    __shared__ float s_norm[KC];   // 1 KB: code norms for the current stage

    const int t  = threadIdx.x;
    const int n0 = blockIdx.x * 512 + t;
    const int n1 = n0 + 256;

    // ---- residuals for 2 points in registers (64 VGPRs) ----
    float r0[DIMS], r1[DIMS];
    {
        const float4* xv0 = (const float4*)(x + (size_t)n0 * DIMS);
        const float4* xv1 = (const float4*)(x + (size_t)n1 * DIMS);
        #pragma unroll
        for (int i = 0; i < 8; ++i) {
            float4 a = xv0[i], b = xv1[i];
            r0[4*i+0] = a.x; r0[4*i+1] = a.y; r0[4*i+2] = a.z; r0[4*i+3] = a.w;
            r1[4*i+0] = b.x; r1[4*i+1] = b.y; r1[4*i+2] = b.z; r1[4*i+3] = b.w;
        }
    }

    float lossAcc = 0.f;
    int idx0[NQ], idx1[NQ];

    for (int q = 0; q < NQ; ++q) {
        __syncthreads();   // previous stage's s_norm reads complete before restage

        // ---- thread t computes norm of code t (global reads, L2-hot) ----
        {
            const float* c = cb + (size_t)q * KC * DIMS + (size_t)t * DIMS;
            float s0 = 0.f, s1 = 0.f, s2 = 0.f, s3 = 0.f;
            #pragma unroll
            for (int d = 0; d < DIMS; d += 4) {
                s0 = fmaf(c[d+0], c[d+0], s0);
                s1 = fmaf(c[d+1], c[d+1], s1);
                s2 = fmaf(c[d+2], c[d+2], s2);
                s3 = fmaf(c[d+3], c[d+3], s3);
            }
            s_norm[t] = (s0 + s1) + (s2 + s3);
        }
        __syncthreads();

        // ---- ||r||^2 per point (loss only) ----
        float rn0, rn1;
        {
            float u0=0.f,u1=0.f,u2=0.f,u3=0.f, v0=0.f,v1=0.f,v2=0.f,v3=0.f;
            #pragma unroll
            for (int d = 0; d < DIMS; d += 4) {
                u0 = fmaf(r0[d+0], r0[d+0], u0);
                u1 = fmaf(r0[d+1], r0[d+1], u1);
                u2 = fmaf(r0[d+2], r0[d+2], u2);
                u3 = fmaf(r0[d+3], r0[d+3], u3);
                v0 = fmaf(r1[d+0], r1[d+0], v0);
                v1 = fmaf(r1[d+1], r1[d+1], v1);
                v2 = fmaf(r1[d+2], r1[d+2], v2);
                v3 = fmaf(r1[d+3], r1[d+3], v3);
            }
            rn0 = (u0 + u1) + (u2 + u3);
            rn1 = (v0 + v1) + (v2 + v3);
        }

        // ---- hot loop: codebook rows in SGPRs, A/B double-buffered ----
        const float* cbq = cb + (size_t)q * KC * DIMS;   // wave-uniform pointer
        float best0 = 3.402823466e38f, best1 = 3.402823466e38f;
        int   bi0 = 0, bi1 = 0;

        float rowA[DIMS], rowB[DIMS];
        LOAD_ROW(rowA, 0)
        for (int k = 0; k < KC; k += 2) {
            LOAD_ROW(rowB, k + 1)                 // prefetch k+1
            SCORE_ROW(rowA, k)
            LOAD_ROW(rowA, (k + 2) & (KC - 1))    // prefetch k+2 (wraps harmlessly)
            SCORE_ROW(rowB, k + 1)
        }

        idx0[q] = bi0;  idx1[q] = bi1;
        lossAcc += (best0 + rn0) + (best1 + rn1);   // == sum of min squared dists

        // ---- gather chosen codes from global (L2-hot), update residuals ----
        const float4* c0 = (const float4*)(cbq + (size_t)bi0 * DIMS);
        const float4* c1 = (const float4*)(cbq + (size_t)bi1 * DIMS);
        #pragma unroll
        for (int i = 0; i < 8; ++i) {
            float4 a = c0[i], b = c1[i];
            r0[4*i+0] -= a.x; r0[4*i+1] -= a.y; r0[4*i+2] -= a.z; r0[4*i+3] -= a.w;
            r1[4*i+0] -= b.x; r1[4*i+1] -= b.y; r1[4*i+2] -= b.z; r1[4*i+3] -= b.w;
        }
    }

    // ---- epilogue: x_q = x - r_final (reload x; L3-hot) ----
    {
        const float4* xv0 = (const float4*)(x + (size_t)n0 * DIMS);
        const float4* xv1 = (const float4*)(x + (size_t)n1 * DIMS);
        float4* ov0 = (float4*)(out_xq + (size_t)n0 * DIMS);
        float4* ov1 = (float4*)(out_xq + (size_t)n1 * DIMS);
        #pragma unroll
        for (int i = 0; i < 8; ++i) {
            float4 xa = xv0[i], xb = xv1[i];
            ov0[i] = make_float4(xa.x - r0[4*i+0], xa.y - r0[4*i+1],
                                 xa.z - r0[4*i+2], xa.w - r0[4*i+3]);
            ov1[i] = make_float4(xb.x - r1[4*i+0], xb.y - r1[4*i+1],
                                 xb.z - r1[4*i+2], xb.w - r1[4*i+3]);
        }
    }

    // ---- indices ----
    #pragma unroll
    for (int q = 0; q < NQ; ++q) {
        out_idx[(size_t)n0 * NQ + q] = (float)idx0[q];
        out_idx[(size_t)n1 * NQ + q] = (float)idx1[q];
    }

    // ---- loss: wave -> block -> one atomicAdd ----
    float v = lossAcc;
    #pragma unroll
    for (int off = 32; off > 0; off >>= 1)
        v += __shfl_down(v, off, 64);

    __shared__ float s_ws[4];
    const int wid = threadIdx.x >> 6;
    if ((threadIdx.x & 63) == 0) s_ws[wid] = v;
    __syncthreads();
    if (threadIdx.x == 0) {
        const float blockSum = (s_ws[0] + s_ws[1]) + (s_ws[2] + s_ws[3]);
        const float nTotal = (float)(gridDim.x * 512);
        const float scale = (1.0f + BETA) / ((float)NQ * nTotal * (float)DIMS);
        atomicAdd(out_loss, blockSum * scale);
    }
}

extern "C" void kernel_launch(void* const* d_in, const int* in_sizes, int n_in,
                              void* d_out, int out_size, void* d_ws, size_t ws_size,
                              hipStream_t stream) {
    const float* x  = (const float*)d_in[0];   // [N, 32]
    const float* cb = (const float*)d_in[1];   // [4, 256, 32]
    float* out = (float*)d_out;

    const int N = in_sizes[0] / DIMS;          // 262144
    float* out_xq   = out;
    float* out_loss = out + (size_t)N * DIMS;
    float* out_idx  = out + (size_t)N * DIMS + 1;

    hipMemsetAsync(out_loss, 0, sizeof(float), stream);

    rvq_kernel<<<dim3(N / 512), dim3(256), 0, stream>>>(x, cb, out_xq, out_loss, out_idx);
}

// Round 4
// 266.256 us; speedup vs baseline: 1.8279x; 1.3220x over previous
//
#include <hip/hip_runtime.h>

// Problem constants: N=262144, D=32, Q=4, K=256
#define DIMS 32
#define NQ   4
#define KC   256
#define BETA 0.25f
#define LDSTRIDE 40            // shorts per code row (32 + 8 pad) -> 80 B, 2-way banks (free)
#define FLTMAX 3.402823466e38f

typedef __attribute__((ext_vector_type(8))) short  short8;   // 8 bf16 (4 VGPRs)
typedef __attribute__((ext_vector_type(4))) float  floatx4;  // MFMA acc

static __device__ __forceinline__ short f2bf(float f) {      // RTNE fp32 -> bf16
    union { float f; unsigned u; } v; v.f = f;
    unsigned r = v.u + 0x7FFF + ((v.u >> 16) & 1);
    return (short)(r >> 16);
}
static __device__ __forceinline__ float bf2f(short b) {
    union { float f; unsigned u; } v;
    v.u = ((unsigned)(unsigned short)b) << 16;
    return v.f;
}

// Each wave: 32 points (2 groups of 16). Residual layout == MFMA A-fragment:
// lane l holds dims (l>>4)*8 .. +7 of point base + g*16 + (l&15).
// D (C-layout): row(point) = (l>>4)*4 + i, col(code) = l&15.
__launch_bounds__(256, 2)
__global__ void rvq_kernel(const float* __restrict__ x,
                           const float* __restrict__ cb,      // [NQ, KC, DIMS]
                           float* __restrict__ out_xq,        // [N, DIMS]
                           float* __restrict__ out_loss,      // [1] pre-zeroed
                           float* __restrict__ out_idx)       // [N, NQ] as float
{
    __shared__ __align__(16) short s_hi[KC * LDSTRIDE];   // 20 KB
    __shared__ __align__(16) short s_lo[KC * LDSTRIDE];   // 20 KB
    __shared__ float s_norm[KC];                          // 1 KB
    __shared__ float s_ws[4];

    const int t  = threadIdx.x;
    const int l  = t & 63;
    const int w  = t >> 6;
    const int qo = l >> 4;       // dim-octet owner (0..3)
    const int cl = l & 15;       // point-within-group / code-within-tile lane

    const int base = blockIdx.x * 128 + w * 32;

    // ---- residuals (A-fragment layout), 16 VGPRs ----
    float r[2][8];
    #pragma unroll
    for (int g = 0; g < 2; ++g) {
        const float4* xp = (const float4*)(x + (size_t)(base + g*16 + cl) * DIMS + qo * 8);
        float4 a = xp[0], b = xp[1];
        r[g][0]=a.x; r[g][1]=a.y; r[g][2]=a.z; r[g][3]=a.w;
        r[g][4]=b.x; r[g][5]=b.y; r[g][6]=b.z; r[g][7]=b.w;
    }

    float la = 0.f;   // loss partial: sum over own dims of ||r_new||^2, all stages

    for (int q = 0; q < NQ; ++q) {
        const float* cbq = cb + (size_t)q * KC * DIMS;
        __syncthreads();   // previous stage's LDS consumers done

        // ---- stage: norms (fp32, exact) ----
        {
            const float4* c4 = (const float4*)(cbq + (size_t)t * DIMS);
            float s0=0.f,s1=0.f,s2=0.f,s3=0.f;
            #pragma unroll
            for (int j = 0; j < 8; ++j) {
                float4 f = c4[j];
                s0 = fmaf(f.x,f.x,s0); s1 = fmaf(f.y,f.y,s1);
                s2 = fmaf(f.z,f.z,s2); s3 = fmaf(f.w,f.w,s3);
            }
            s_norm[t] = (s0+s1)+(s2+s3);
        }
        // ---- stage: split-bf16 codebook into LDS (coalesced float4 reads) ----
        {
            const float4* call = (const float4*)cbq;
            #pragma unroll
            for (int j = 0; j < 8; ++j) {
                int idx  = j * 256 + t;
                float4 f = call[idx];
                int code = idx >> 3;
                int dim  = (idx & 7) << 2;
                short h0=f2bf(f.x), h1=f2bf(f.y), h2=f2bf(f.z), h3=f2bf(f.w);
                short e0=f2bf(f.x-bf2f(h0)), e1=f2bf(f.y-bf2f(h1)),
                      e2=f2bf(f.z-bf2f(h2)), e3=f2bf(f.w-bf2f(h3));
                int off = code * LDSTRIDE + dim;
                int2 hp, lp;
                hp.x = (h0 & 0xFFFF) | ((int)h1 << 16);
                hp.y = (h2 & 0xFFFF) | ((int)h3 << 16);
                lp.x = (e0 & 0xFFFF) | ((int)e1 << 16);
                lp.y = (e2 & 0xFFFF) | ((int)e3 << 16);
                *(int2*)(&s_hi[off]) = hp;
                *(int2*)(&s_lo[off]) = lp;
            }
        }
        __syncthreads();

        // ---- A-fragments (split bf16 of residual) ----
        short8 ah[2], al[2];
        #pragma unroll
        for (int g = 0; g < 2; ++g) {
            #pragma unroll
            for (int j = 0; j < 8; ++j) {
                short h = f2bf(r[g][j]);
                ah[g][j] = h;
                al[g][j] = f2bf(r[g][j] - bf2f(h));
            }
        }

        // ---- ||r||^2 per point (for eps scaling) ----
        float rn[2];
        #pragma unroll
        for (int g = 0; g < 2; ++g) {
            float p0=0.f;
            #pragma unroll
            for (int j = 0; j < 8; ++j) p0 = fmaf(r[g][j], r[g][j], p0);
            p0 += __shfl_xor(p0, 16);
            p0 += __shfl_xor(p0, 32);
            rn[g] = p0;
        }

        // ---- MFMA tile loop: 16 tiles of 16 codes, track (m1,i1,m2) per row ----
        float m1[2][4], m2[2][4]; int i1[2][4];
        #pragma unroll
        for (int g = 0; g < 2; ++g)
            #pragma unroll
            for (int i = 0; i < 4; ++i) { m1[g][i] = FLTMAX; m2[g][i] = FLTMAX; i1[g][i] = 0; }

        #pragma unroll 4
        for (int tt = 0; tt < 16; ++tt) {
            int code = tt * 16 + cl;
            short8 bh = *(const short8*)(&s_hi[code * LDSTRIDE + qo * 8]);
            short8 bl = *(const short8*)(&s_lo[code * LDSTRIDE + qo * 8]);
            float nrm = s_norm[code];
            #pragma unroll
            for (int g = 0; g < 2; ++g) {
                floatx4 acc = {0.f, 0.f, 0.f, 0.f};
                acc = __builtin_amdgcn_mfma_f32_16x16x32_bf16(ah[g], bh, acc, 0, 0, 0);
                acc = __builtin_amdgcn_mfma_f32_16x16x32_bf16(ah[g], bl, acc, 0, 0, 0);
                acc = __builtin_amdgcn_mfma_f32_16x16x32_bf16(al[g], bh, acc, 0, 0, 0);
                #pragma unroll
                for (int i = 0; i < 4; ++i) {
                    float sc = fmaf(-2.f, acc[i], nrm);
                    bool lt  = sc < m1[g][i];
                    // m2 = median(sc, m1_old, m2_old)
                    float mn = fminf(sc, m1[g][i]);
                    float mx = fmaxf(sc, m1[g][i]);
                    m2[g][i] = fmaxf(mn, fminf(mx, m2[g][i]));
                    m1[g][i] = mn;
                    i1[g][i] = lt ? code : i1[g][i];
                }
            }
        }

        // ---- reduce (m1,i1,m2) across the 16 lanes sharing each row-quad ----
        #pragma unroll
        for (int g = 0; g < 2; ++g) {
            #pragma unroll
            for (int off = 1; off <= 8; off <<= 1) {
                #pragma unroll
                for (int i = 0; i < 4; ++i) {
                    float m1o = __shfl_xor(m1[g][i], off);
                    int   i1o = __shfl_xor(i1[g][i], off);
                    float m2o = __shfl_xor(m2[g][i], off);
                    bool take = (m1o < m1[g][i]) || (m1o == m1[g][i] && i1o < i1[g][i]);
                    float loser = take ? m1[g][i] : m1o;
                    m1[g][i] = take ? m1o : m1[g][i];
                    i1[g][i] = take ? i1o : i1[g][i];
                    m2[g][i] = fminf(fminf(m2[g][i], m2o), loser);
                }
            }
        }

        // ---- broadcast per-point (bi, m1, m2) to the lanes owning that point ----
        int bip[2]; bool flg[2];
        #pragma unroll
        for (int g = 0; g < 2; ++g) {
            int src = (cl >> 2) * 16;
            int  b0=__shfl(i1[g][0],src), b1=__shfl(i1[g][1],src),
                 b2=__shfl(i1[g][2],src), b3=__shfl(i1[g][3],src);
            float f0=__shfl(m1[g][0],src), f1=__shfl(m1[g][1],src),
                  f2=__shfl(m1[g][2],src), f3=__shfl(m1[g][3],src);
            float h0=__shfl(m2[g][0],src), h1=__shfl(m2[g][1],src),
                  h2=__shfl(m2[g][2],src), h3=__shfl(m2[g][3],src);
            int sel = l & 3;
            bip[g]    = (sel==0)?b0 : (sel==1)?b1 : (sel==2)?b2 : b3;
            float mm1 = (sel==0)?f0 : (sel==1)?f1 : (sel==2)?f2 : f3;
            float mm2 = (sel==0)?h0 : (sel==1)?h1 : (sel==2)?h2 : h3;
            float eps = 1e-3f * sqrtf(rn[g]) + 1e-6f;   // 4x worst-case bf16x3 bound
            flg[g] = (mm2 - mm1) < eps;
        }

        // ---- rare: exact fp32 wave-cooperative rescan of ambiguous points ----
        #pragma unroll
        for (int g = 0; g < 2; ++g) {
            unsigned long long bm = __ballot((l < 16) && flg[g]);
            while (bm) {
                int p = __ffsll(bm) - 1;
                bm &= bm - 1;
                float rp[32];
                #pragma unroll
                for (int qq = 0; qq < 4; ++qq)
                    #pragma unroll
                    for (int j = 0; j < 8; ++j)
                        rp[qq*8 + j] = __shfl(r[g][j], qq*16 + p);
                float bests = FLTMAX; int bestk = 0;
                #pragma unroll
                for (int c = 0; c < 4; ++c) {
                    int k = (c << 6) + l;
                    const float4* ck = (const float4*)(cbq + (size_t)k * DIMS);
                    float a0=0.f,a1=0.f,a2=0.f,a3=0.f;
                    #pragma unroll
                    for (int j = 0; j < 8; ++j) {
                        float4 f = ck[j];
                        a0 = fmaf(rp[4*j+0], f.x, a0);
                        a1 = fmaf(rp[4*j+1], f.y, a1);
                        a2 = fmaf(rp[4*j+2], f.z, a2);
                        a3 = fmaf(rp[4*j+3], f.w, a3);
                    }
                    float sc = fmaf(-2.f, (a0+a1)+(a2+a3), s_norm[k]);
                    bool lt = sc < bests;
                    bests = lt ? sc : bests;  bestk = lt ? k : bestk;
                }
                #pragma unroll
                for (int off = 1; off < 64; off <<= 1) {
                    float so = __shfl_xor(bests, off);
                    int   ko = __shfl_xor(bestk, off);
                    bool take = (so < bests) || (so == bests && ko < bestk);
                    bests = take ? so : bests;
                    bestk = take ? ko : bestk;
                }
                if (cl == p) bip[g] = bestk;   // all 4 dim-octet lanes fix up
            }
        }

        // ---- gather chosen codes, update residual, exact-fp32 loss, indices ----
        #pragma unroll
        for (int g = 0; g < 2; ++g) {
            const float4* cq = (const float4*)(cbq + (size_t)bip[g] * DIMS + qo * 8);
            float4 c0 = cq[0], c1 = cq[1];
            r[g][0]-=c0.x; r[g][1]-=c0.y; r[g][2]-=c0.z; r[g][3]-=c0.w;
            r[g][4]-=c1.x; r[g][5]-=c1.y; r[g][6]-=c1.z; r[g][7]-=c1.w;
            #pragma unroll
            for (int j = 0; j < 8; ++j) la = fmaf(r[g][j], r[g][j], la);  // ||q-r||^2
            if (l < 16)
                out_idx[(size_t)(base + g*16 + l) * NQ + q] = (float)bip[g];
        }
    }

    // ---- epilogue: x_q = x - r_final ----
    #pragma unroll
    for (int g = 0; g < 2; ++g) {
        size_t o = (size_t)(base + g*16 + cl) * DIMS + qo * 8;
        const float4* xp = (const float4*)(x + o);
        float4 a = xp[0], b = xp[1];
        float4* op = (float4*)(out_xq + o);
        op[0] = make_float4(a.x - r[g][0], a.y - r[g][1], a.z - r[g][2], a.w - r[g][3]);
        op[1] = make_float4(b.x - r[g][4], b.y - r[g][5], b.z - r[g][6], b.w - r[g][7]);
    }

    // ---- loss: wave -> block -> one atomicAdd ----
    float v = la;
    #pragma unroll
    for (int off = 1; off < 64; off <<= 1)
        v += __shfl_xor(v, off);
    if (l == 0) s_ws[w] = v;
    __syncthreads();
    if (t == 0) {
        const float scale = (1.0f + BETA) / ((float)NQ * 262144.0f * (float)DIMS);
        atomicAdd(out_loss, (s_ws[0] + s_ws[1] + s_ws[2] + s_ws[3]) * scale);
    }
}

extern "C" void kernel_launch(void* const* d_in, const int* in_sizes, int n_in,
                              void* d_out, int out_size, void* d_ws, size_t ws_size,
                              hipStream_t stream) {
    const float* x  = (const float*)d_in[0];   // [N, 32]
    const float* cb = (const float*)d_in[1];   // [4, 256, 32]
    float* out = (float*)d_out;

    const int N = in_sizes[0] / DIMS;          // 262144
    float* out_xq   = out;
    float* out_loss = out + (size_t)N * DIMS;
    float* out_idx  = out + (size_t)N * DIMS + 1;

    hipMemsetAsync(out_loss, 0, sizeof(float), stream);

    rvq_kernel<<<dim3(N / 128), dim3(256), 0, stream>>>(x, cb, out_xq, out_loss, out_idx);
}

// Round 5
// 256.755 us; speedup vs baseline: 1.8956x; 1.0370x over previous
//
#include <hip/hip_runtime.h>

// Problem constants: N=262144, D=32, Q=4, K=256
#define DIMS 32
#define NQ   4
#define KC   256
#define BETA 0.25f
#define FLTMAX 3.402823466e38f

typedef __attribute__((ext_vector_type(8))) short  short8;   // 8 bf16 (4 VGPRs)
typedef __attribute__((ext_vector_type(4))) float  floatx4;  // MFMA acc

static __device__ __forceinline__ short f2bf(float f) {      // RTNE fp32 -> bf16
    union { float f; unsigned u; } v; v.f = f;
    unsigned r = v.u + 0x7FFF + ((v.u >> 16) & 1);
    return (short)(r >> 16);
}
static __device__ __forceinline__ float bf2f(short b) {
    union { float f; unsigned u; } v;
    v.u = ((unsigned)(unsigned short)b) << 16;
    return v.f;
}

// Wave layout (verified round 4): A-frag lane l = dims (l>>4)*8.. of point (l&15);
// C-layout row(point) = (l>>4)*4+i, col(code) = l&15.
// LDS B-fragments in exact lane order: entry e = tile*64 + lane, 16 B
//   -> ds_read_b128 at dword 4*l: sequential, conflict-free.
// acc = 0.5*||r||^2 + 0.5*||c||^2 - dot = dist^2/2  (negated A-frags, norm in C-init)
//   -> argmin(acc); code index packed into low 8 mantissa bits, min-reduce carries it.
__launch_bounds__(256, 2)
__global__ void rvq_kernel(const float* __restrict__ x,
                           const float* __restrict__ cb,      // [NQ, KC, DIMS]
                           float* __restrict__ out_xq,        // [N, DIMS]
                           float* __restrict__ out_loss,      // [1] pre-zeroed
                           float* __restrict__ out_idx)       // [N, NQ] as float
{
    __shared__ __align__(16) short s_hi[16 * 64 * 8];   // 16 KB
    __shared__ __align__(16) short s_lo[16 * 64 * 8];   // 16 KB
    __shared__ float s_norm[KC];                        // 1 KB
    __shared__ float s_ws[4];

    const int t  = threadIdx.x;
    const int l  = t & 63;
    const int w  = t >> 6;
    const int qo = l >> 4;       // dim-octet (0..3)
    const int cl = l & 15;       // point-in-group / code-in-tile lane

    // block covers 256 points: 2 batches x 4 waves x 32 points
    const int blk = blockIdx.x * 256;

    // ---- residuals: [batch][group][8 dims], 32 VGPRs ----
    float r[2][2][8];
    #pragma unroll
    for (int b = 0; b < 2; ++b)
        #pragma unroll
        for (int g = 0; g < 2; ++g) {
            const float4* xp = (const float4*)(x + (size_t)(blk + b*128 + w*32 + g*16 + cl) * DIMS + qo * 8);
            float4 a = xp[0], c = xp[1];
            r[b][g][0]=a.x; r[b][g][1]=a.y; r[b][g][2]=a.z; r[b][g][3]=a.w;
            r[b][g][4]=c.x; r[b][g][5]=c.y; r[b][g][6]=c.z; r[b][g][7]=c.w;
        }

    float la = 0.f;   // sum over own dims of ||r_new||^2, all stages/batches

    for (int q = 0; q < NQ; ++q) {
        const float* cbq = cb + (size_t)q * KC * DIMS;
        __syncthreads();   // previous stage's LDS consumers done

        // ---- stage: exact fp32 norms (thread t <-> code t) ----
        {
            const float4* c4 = (const float4*)(cbq + (size_t)t * DIMS);
            float s0=0.f,s1=0.f,s2=0.f,s3=0.f;
            #pragma unroll
            for (int j = 0; j < 8; ++j) {
                float4 f = c4[j];
                s0 = fmaf(f.x,f.x,s0); s1 = fmaf(f.y,f.y,s1);
                s2 = fmaf(f.z,f.z,s2); s3 = fmaf(f.w,f.w,s3);
            }
            s_norm[t] = (s0+s1)+(s2+s3);
        }
        // ---- stage: split-bf16 codebook into lane-ordered B-fragment layout ----
        {
            const float4* call = (const float4*)cbq;
            #pragma unroll
            for (int j = 0; j < 8; ++j) {
                int idx  = j * 256 + t;
                float4 f = call[idx];
                int c  = idx >> 3;       // code
                int dq = idx & 7;        // dim-quad (dims 4dq..4dq+3)
                short h0=f2bf(f.x), h1=f2bf(f.y), h2=f2bf(f.z), h3=f2bf(f.w);
                short e0=f2bf(f.x-bf2f(h0)), e1=f2bf(f.y-bf2f(h1)),
                      e2=f2bf(f.z-bf2f(h2)), e3=f2bf(f.w-bf2f(h3));
                int e  = ((c >> 4) << 6) + ((dq >> 1) << 4) + (c & 15);  // tile*64 + qo*16 + cl
                int so = (e << 3) + ((dq & 1) << 2);                     // short offset
                int2 hp, lp;
                hp.x = (h0 & 0xFFFF) | ((int)h1 << 16);
                hp.y = (h2 & 0xFFFF) | ((int)h3 << 16);
                lp.x = (e0 & 0xFFFF) | ((int)e1 << 16);
                lp.y = (e2 & 0xFFFF) | ((int)e3 << 16);
                *(int2*)(&s_hi[so]) = hp;
                *(int2*)(&s_lo[so]) = lp;
            }
        }
        __syncthreads();

        for (int b = 0; b < 2; ++b) {
            // ---- A-fragments: split bf16 of NEGATED residual ----
            short8 ah[2], al[2];
            #pragma unroll
            for (int g = 0; g < 2; ++g)
                #pragma unroll
                for (int j = 0; j < 8; ++j) {
                    float nr = -r[b][g][j];
                    short h = f2bf(nr);
                    ah[g][j] = h;
                    al[g][j] = f2bf(nr - bf2f(h));
                }

            // ---- ||r||^2 per point; half-norms for own C-rows ----
            float rn[2], hrn[2][4];
            #pragma unroll
            for (int g = 0; g < 2; ++g) {
                float p0 = 0.f;
                #pragma unroll
                for (int j = 0; j < 8; ++j) p0 = fmaf(r[b][g][j], r[b][g][j], p0);
                p0 += __shfl_xor(p0, 16);
                p0 += __shfl_xor(p0, 32);
                rn[g] = p0;
                #pragma unroll
                for (int i = 0; i < 4; ++i)
                    hrn[g][i] = 0.5f * __shfl(rn[g], (qo << 2) + i);
            }

            // ---- MFMA tile loop: packed-index top-2 min tracking ----
            float m1[2][4], m2[2][4];
            #pragma unroll
            for (int g = 0; g < 2; ++g)
                #pragma unroll
                for (int i = 0; i < 4; ++i) { m1[g][i] = FLTMAX; m2[g][i] = FLTMAX; }

            #pragma unroll 4
            for (int tt = 0; tt < 16; ++tt) {
                const short8 bh = *(const short8*)(&s_hi[((tt << 6) + l) << 3]);
                const short8 bl = *(const short8*)(&s_lo[((tt << 6) + l) << 3]);
                const int   code = (tt << 4) + cl;
                const float hn   = 0.5f * s_norm[code];
                #pragma unroll
                for (int g = 0; g < 2; ++g) {
                    floatx4 acc = {hrn[g][0] + hn, hrn[g][1] + hn,
                                   hrn[g][2] + hn, hrn[g][3] + hn};
                    acc = __builtin_amdgcn_mfma_f32_16x16x32_bf16(ah[g], bh, acc, 0, 0, 0);
                    acc = __builtin_amdgcn_mfma_f32_16x16x32_bf16(ah[g], bl, acc, 0, 0, 0);
                    acc = __builtin_amdgcn_mfma_f32_16x16x32_bf16(al[g], bh, acc, 0, 0, 0);
                    #pragma unroll
                    for (int i = 0; i < 4; ++i) {
                        unsigned u = __float_as_uint(acc[i]);
                        float pm = __uint_as_float((u & 0xFFFFFF00u) | (unsigned)code);
                        float mx = fmaxf(pm, m1[g][i]);
                        m1[g][i] = fminf(pm, m1[g][i]);
                        m2[g][i] = fminf(m2[g][i], mx);
                    }
                }
            }

            // ---- reduce (m1,m2) across the 16 lanes sharing each row-quad ----
            #pragma unroll
            for (int g = 0; g < 2; ++g)
                #pragma unroll
                for (int off = 1; off <= 8; off <<= 1)
                    #pragma unroll
                    for (int i = 0; i < 4; ++i) {
                        float m1o = __shfl_xor(m1[g][i], off);
                        float m2o = __shfl_xor(m2[g][i], off);
                        m2[g][i] = fminf(fminf(m2[g][i], m2o), fmaxf(m1[g][i], m1o));
                        m1[g][i] = fminf(m1[g][i], m1o);
                    }

            // ---- broadcast per-point (m1,m2) to point-owner lanes ----
            int bip[2]; bool flg[2];
            #pragma unroll
            for (int g = 0; g < 2; ++g) {
                const int src = (cl >> 2) << 4;
                float f0=__shfl(m1[g][0],src), f1=__shfl(m1[g][1],src),
                      f2=__shfl(m1[g][2],src), f3=__shfl(m1[g][3],src);
                float h0=__shfl(m2[g][0],src), h1=__shfl(m2[g][1],src),
                      h2=__shfl(m2[g][2],src), h3=__shfl(m2[g][3],src);
                int sel = l & 3;
                float mm1 = (sel==0)?f0 : (sel==1)?f1 : (sel==2)?f2 : f3;
                float mm2 = (sel==0)?h0 : (sel==1)?h1 : (sel==2)?h2 : h3;
                unsigned ub = __float_as_uint(mm1);
                bip[g] = (int)(ub & 0xFFu);
                float a1 = __uint_as_float(ub & 0xFFFFFF00u);
                float a2 = __uint_as_float(__float_as_uint(mm2) & 0xFFFFFF00u);
                // eps (acc units = sc/2): 2x round-4 margin + packing-quant term
                float eps = fmaf(sqrtf(rn[g]), 1e-3f, fmaf(fabsf(a1), 1e-4f, 1e-6f));
                flg[g] = (a2 - a1) < eps;
            }

            // ---- rare: exact fp32 wave-cooperative rescan of ambiguous points ----
            #pragma unroll
            for (int g = 0; g < 2; ++g) {
                unsigned long long bm = __ballot((l < 16) && flg[g]);
                while (bm) {
                    int p = __ffsll(bm) - 1;
                    bm &= bm - 1;
                    float rp[32];
                    #pragma unroll
                    for (int qq = 0; qq < 4; ++qq)
                        #pragma unroll
                        for (int j = 0; j < 8; ++j)
                            rp[qq*8 + j] = __shfl(r[b][g][j], qq*16 + p);
                    float bests = FLTMAX; int bestk = 0;
                    #pragma unroll
                    for (int c = 0; c < 4; ++c) {
                        int k = (c << 6) + l;
                        const float4* ck = (const float4*)(cbq + (size_t)k * DIMS);
                        float a0=0.f,a1=0.f,a2=0.f,a3=0.f;
                        #pragma unroll
                        for (int j = 0; j < 8; ++j) {
                            float4 f = ck[j];
                            a0 = fmaf(rp[4*j+0], f.x, a0);
                            a1 = fmaf(rp[4*j+1], f.y, a1);
                            a2 = fmaf(rp[4*j+2], f.z, a2);
                            a3 = fmaf(rp[4*j+3], f.w, a3);
                        }
                        float sc = fmaf(-2.f, (a0+a1)+(a2+a3), s_norm[k]);
                        bool lt = sc < bests;
                        bests = lt ? sc : bests;  bestk = lt ? k : bestk;
                    }
                    #pragma unroll
                    for (int off = 1; off < 64; off <<= 1) {
                        float so = __shfl_xor(bests, off);
                        int   ko = __shfl_xor(bestk, off);
                        bool take = (so < bests) || (so == bests && ko < bestk);
                        bests = take ? so : bests;
                        bestk = take ? ko : bestk;
                    }
                    if (cl == p) bip[g] = bestk;
                }
            }

            // ---- gather chosen codes, update residual, exact-fp32 loss, indices ----
            #pragma unroll
            for (int g = 0; g < 2; ++g) {
                const float4* cq = (const float4*)(cbq + (size_t)bip[g] * DIMS + qo * 8);
                float4 c0 = cq[0], c1 = cq[1];
                r[b][g][0]-=c0.x; r[b][g][1]-=c0.y; r[b][g][2]-=c0.z; r[b][g][3]-=c0.w;
                r[b][g][4]-=c1.x; r[b][g][5]-=c1.y; r[b][g][6]-=c1.z; r[b][g][7]-=c1.w;
                #pragma unroll
                for (int j = 0; j < 8; ++j) la = fmaf(r[b][g][j], r[b][g][j], la);
                if (l < 16)
                    out_idx[(size_t)(blk + b*128 + w*32 + g*16 + l) * NQ + q] = (float)bip[g];
            }
        }
    }

    // ---- epilogue: x_q = x - r_final ----
    #pragma unroll
    for (int b = 0; b < 2; ++b)
        #pragma unroll
        for (int g = 0; g < 2; ++g) {
            size_t o = (size_t)(blk + b*128 + w*32 + g*16 + cl) * DIMS + qo * 8;
            const float4* xp = (const float4*)(x + o);
            float4 a = xp[0], c = xp[1];
            float4* op = (float4*)(out_xq + o);
            op[0] = make_float4(a.x - r[b][g][0], a.y - r[b][g][1],
                                a.z - r[b][g][2], a.w - r[b][g][3]);
            op[1] = make_float4(c.x - r[b][g][4], c.y - r[b][g][5],
                                c.z - r[b][g][6], c.w - r[b][g][7]);
        }

    // ---- loss: wave -> block -> one atomicAdd ----
    float v = la;
    #pragma unroll
    for (int off = 1; off < 64; off <<= 1)
        v += __shfl_xor(v, off);
    if (l == 0) s_ws[w] = v;
    __syncthreads();
    if (t == 0) {
        const float scale = (1.0f + BETA) / ((float)NQ * 262144.0f * (float)DIMS);
        atomicAdd(out_loss, (s_ws[0] + s_ws[1] + s_ws[2] + s_ws[3]) * scale);
    }
}

extern "C" void kernel_launch(void* const* d_in, const int* in_sizes, int n_in,
                              void* d_out, int out_size, void* d_ws, size_t ws_size,
                              hipStream_t stream) {
    const float* x  = (const float*)d_in[0];   // [N, 32]
    const float* cb = (const float*)d_in[1];   // [4, 256, 32]
    float* out = (float*)d_out;

    const int N = in_sizes[0] / DIMS;          // 262144
    float* out_xq   = out;
    float* out_loss = out + (size_t)N * DIMS;
    float* out_idx  = out + (size_t)N * DIMS + 1;

    hipMemsetAsync(out_loss, 0, sizeof(float), stream);

    rvq_kernel<<<dim3(N / 256), dim3(256), 0, stream>>>(x, cb, out_xq, out_loss, out_idx);
}